// Round 3
// baseline (119.020 us; speedup 1.0000x reference)
//
#include <hip/hip_runtime.h>
#include <hip/hip_cooperative_groups.h>

namespace cg = cooperative_groups;

#define DIM 512
#define TEMP 0.5f
#define EPS 1e-8f
#define BT 512            // 8 waves per block
#define ROWS_PER_BLK 64   // 8 rows per wave, fully unrolled
#define NBLK 256          // one block per CU (co-resident: cooperative launch)
#define PSTRIDE 516       // 512 s-elements + 1 diag + 3 pad (float4-aligned stride)

// Single cooperative kernel:
//   stage 1: block b reduces rows [64b, 64b+64) -> partial s-vector (512) + diag,
//            written to part[b*516 + ...]. One wave per row; lane l holds row
//            elements [4l,4l+4) and [256+4l,...) via two coalesced float4 loads.
//   grid.sync()
//   stage 2: block 0 folds 256 partials (L2-hot, ~525 KB) -> scalar.
__global__ __launch_bounds__(BT) void fused_kernel(const float* __restrict__ x,
                                                   float* __restrict__ part,
                                                   float* __restrict__ out, int N) {
    const int tid  = threadIdx.x;
    const int wave = tid >> 6;
    const int lane = tid & 63;
    const int rowBase = blockIdx.x * ROWS_PER_BLK;

    float4 accA = make_float4(0.f, 0.f, 0.f, 0.f);
    float4 accB = make_float4(0.f, 0.f, 0.f, 0.f);
    float diag = 0.f;

    if (rowBase + ROWS_PER_BLK <= N) {
        #pragma unroll
        for (int rr = 0; rr < 8; ++rr) {
            const int row = rowBase + wave + rr * 8;
            const float4* p = (const float4*)(x + (size_t)row * DIM);
            const float4 a = p[lane];
            const float4 b = p[lane + 64];
            float ss = a.x * a.x + a.y * a.y + a.z * a.z + a.w * a.w
                     + b.x * b.x + b.y * b.y + b.z * b.z + b.w * b.w;
            #pragma unroll
            for (int off = 1; off < 64; off <<= 1) ss += __shfl_xor(ss, off);
            const float inv = 1.0f / fmaxf(sqrtf(ss), EPS);
            if (lane == 0) diag += ss * inv * inv;
            accA.x = fmaf(a.x, inv, accA.x); accA.y = fmaf(a.y, inv, accA.y);
            accA.z = fmaf(a.z, inv, accA.z); accA.w = fmaf(a.w, inv, accA.w);
            accB.x = fmaf(b.x, inv, accB.x); accB.y = fmaf(b.y, inv, accB.y);
            accB.z = fmaf(b.z, inv, accB.z); accB.w = fmaf(b.w, inv, accB.w);
        }
    } else {
        for (int rr = 0; rr < 8; ++rr) {
            const int row = rowBase + wave + rr * 8;
            if (row >= N) break;
            const float4* p = (const float4*)(x + (size_t)row * DIM);
            const float4 a = p[lane];
            const float4 b = p[lane + 64];
            float ss = a.x * a.x + a.y * a.y + a.z * a.z + a.w * a.w
                     + b.x * b.x + b.y * b.y + b.z * b.z + b.w * b.w;
            #pragma unroll
            for (int off = 1; off < 64; off <<= 1) ss += __shfl_xor(ss, off);
            const float inv = 1.0f / fmaxf(sqrtf(ss), EPS);
            if (lane == 0) diag += ss * inv * inv;
            accA.x = fmaf(a.x, inv, accA.x); accA.y = fmaf(a.y, inv, accA.y);
            accA.z = fmaf(a.z, inv, accA.z); accA.w = fmaf(a.w, inv, accA.w);
            accB.x = fmaf(b.x, inv, accB.x); accB.y = fmaf(b.y, inv, accB.y);
            accB.z = fmaf(b.z, inv, accB.z); accB.w = fmaf(b.w, inv, accB.w);
        }
    }

    // Combine the 8 waves' partials in LDS (float4 stores, conflict-free).
    __shared__ float sred[8][DIM];
    __shared__ float dred[8];
    *(float4*)&sred[wave][lane * 4]       = accA;
    *(float4*)&sred[wave][256 + lane * 4] = accB;
    if (lane == 0) dred[wave] = diag;
    __syncthreads();

    float v = 0.f;
    #pragma unroll
    for (int w = 0; w < 8; ++w) v += sred[w][tid];
    part[(size_t)blockIdx.x * PSTRIDE + tid] = v;
    if (tid == 0) {
        float d = 0.f;
        #pragma unroll
        for (int w = 0; w < 8; ++w) d += dred[w];
        part[(size_t)blockIdx.x * PSTRIDE + DIM] = d;
    }

    cg::this_grid().sync();

    // Stage 2: block 0 only. Partials are L2-hot (just written device-wide).
    if (blockIdx.x != 0) return;

    float acc = 0.f;
    #pragma unroll 16
    for (int b = 0; b < NBLK; ++b) acc += part[(size_t)b * PSTRIDE + tid];
    float q = acc * acc;                                    // -> ||s||^2
    if (tid < NBLK) q -= part[(size_t)tid * PSTRIDE + DIM]; // subtract diag partials
    #pragma unroll
    for (int off = 1; off < 64; off <<= 1) q += __shfl_xor(q, off);

    if (lane == 0) dred[wave] = q;   // reuse LDS (post-sync, block 0 only)
    __syncthreads();
    if (tid == 0) {
        float tot = 0.f;
        #pragma unroll
        for (int w = 0; w < 8; ++w) tot += dred[w];
        out[0] = tot / (TEMP * (float)N);
    }
}

extern "C" void kernel_launch(void* const* d_in, const int* in_sizes, int n_in,
                              void* d_out, int out_size, void* d_ws, size_t ws_size,
                              hipStream_t stream) {
    const float* x = (const float*)d_in[0];
    float* part = (float*)d_ws;
    float* out = (float*)d_out;
    int N = in_sizes[0] / DIM;  // 16384

    void* args[] = {(void*)&x, (void*)&part, (void*)&out, (void*)&N};
    hipLaunchCooperativeKernel((void*)fused_kernel, dim3(NBLK), dim3(BT),
                               args, 0, stream);
}